// Round 5
// baseline (358.875 us; speedup 1.0000x reference)
//
#include <hip/hip_runtime.h>
#include <hip/hip_bf16.h>

typedef unsigned int uint_t;
typedef __attribute__((ext_vector_type(8))) short bf16x8;   // MFMA A/B frag (4 VGPRs)
typedef __attribute__((ext_vector_type(4))) float f32x4;    // MFMA C/D frag

#define NPTS 50000
#define DIM  64
#define KNB  16
#define GPW  8                  // points per wave (one group per wave)
#define NGROUPS (NPTS / GPW)    // 6250
#define WPB  4                  // waves per block
#define NBLOCKS ((NGROUPS + WPB - 1) / WPB)

// ws layout in 32-bit words: frag images are [f*256 + lane*4 + w]
#define FR_WA    0       // Wa frag image (8 frags)
#define FR_PSIG  2048    // -(Wpsi@Wg) frag image
#define FR_WG    4096    // Wg, rows sigma-permuted, frag image
#define FR_PHIG  6144    // (Wphi@Wg) frag image
#define WC4      8192    // 64 x float4 (wcx,wcy,wcz,wbc)
#define GB       8448    // (bphi-bpsi)@Wg + bg
#define BA       8512    // b_alpha

__device__ __forceinline__ uint_t pk(float a, float b) {
    union { __hip_bfloat162 h; uint_t u; } cv;
    cv.h = __float22bfloat162_rn(float2{a, b});
    return cv.u;
}

union Frag { uint_t u[4]; bf16x8 s; uint4 v; };

// sigma: row-permutation of Wg so the utr writer's packed pairs land as the
// reader's consecutive A-frag k-dim pairs.
__device__ __forceinline__ int sigma(int k) {
    int t = k >> 1;
    return (t & 15) + 32 * (t >> 4) + 16 * (k & 1);
}

__global__ void pt_prep(const float* __restrict__ Wphi, const float* __restrict__ bphi,
                        const float* __restrict__ Wpsi, const float* __restrict__ bpsi,
                        const float* __restrict__ Wa,   const float* __restrict__ ba,
                        const float* __restrict__ Wg,   const float* __restrict__ bg,
                        const float* __restrict__ Wd1,  const float* __restrict__ bd1,
                        const float* __restrict__ Wd2,  const float* __restrict__ bd2,
                        float* __restrict__ ws) {
    int b = blockIdx.x, t = threadIdx.x;
    uint_t* wsu = (uint_t*)ws;
    if (b < 32) {
        int gid  = b * 256 + t;             // [0, 8192)
        int img  = gid >> 11;               // 0..3
        int rem  = gid & 2047;
        int f    = rem >> 8;                // 0..7  (nt = f>>1, s = f&1)
        int lane = (rem >> 2) & 63;
        int w    = rem & 3;
        int k0   = (f & 1) * 32 + (lane >> 4) * 8 + 2 * w;
        int k1   = k0 + 1;
        int n    = (f >> 1) * 16 + (lane & 15);
        float v0, v1;
        if (img == 0) {                     // Wa
            v0 = Wa[k0 * 64 + n]; v1 = Wa[k1 * 64 + n];
            wsu[FR_WA + rem] = pk(v0, v1);
        } else if (img == 1) {              // -(Wpsi@Wg)
            float a0 = 0.f, a1 = 0.f;
            for (int c = 0; c < 64; ++c) {
                float wgc = Wg[c * 64 + n];
                a0 += Wpsi[k0 * 64 + c] * wgc;
                a1 += Wpsi[k1 * 64 + c] * wgc;
            }
            wsu[FR_PSIG + rem] = pk(-a0, -a1);
        } else if (img == 2) {              // Wg sigma-row-permuted
            v0 = Wg[sigma(k0) * 64 + n]; v1 = Wg[sigma(k1) * 64 + n];
            wsu[FR_WG + rem] = pk(v0, v1);
        } else {                            // Wphi@Wg
            float a0 = 0.f, a1 = 0.f;
            for (int c = 0; c < 64; ++c) {
                float wgc = Wg[c * 64 + n];
                a0 += Wphi[k0 * 64 + c] * wgc;
                a1 += Wphi[k1 * 64 + c] * wgc;
            }
            wsu[FR_PHIG + rem] = pk(a0, a1);
        }
    } else if (t < 64) {
        float wx = 0.f, wy = 0.f, wz = 0.f;
        for (int m = 0; m < 64; ++m) {
            float w2 = Wd2[m * 64 + t];
            wx += Wd1[m] * w2;
            wy += Wd1[64 + m] * w2;
            wz += Wd1[128 + m] * w2;
        }
        float wb = bd2[t];
        for (int m = 0; m < 64; ++m) wb += bd1[m] * Wd2[m * 64 + t];
        ws[WC4 + t * 4 + 0] = wx;
        ws[WC4 + t * 4 + 1] = wy;
        ws[WC4 + t * 4 + 2] = wz;
        ws[WC4 + t * 4 + 3] = wb;
        float g = bg[t];
        for (int c = 0; c < 64; ++c) g += (bphi[c] - bpsi[c]) * Wg[c * 64 + t];
        ws[GB + t] = g;
        ws[BA + t] = ba[t];
    }
}

#define MFMA(A, B, C) __builtin_amdgcn_mfma_f32_16x16x32_bf16((A), (B), (C), 0, 0, 0)

// per-wave LDS (words): phig 8*65=520 | utr 16*34=544 | dxyz 2*16*4=128 | pxyz 32
#define WAREA 1224

__global__ __launch_bounds__(256, 3)
void pt_main(const float* __restrict__ pxyz, const float* __restrict__ pfeat,
             const float* __restrict__ nxyz, const float* __restrict__ nfeat,
             const float* __restrict__ ws,   float* __restrict__ out) {
    __shared__ uint4 wfr[1536];               // wa | wpsig | wg frag images: 24 KB
    __shared__ float lds[WPB][WAREA];         // 19.6 KB

    const int t    = threadIdx.x;
    const int wv   = t >> 6;
    const int lane = t & 63;
    const int c16  = lane & 15;
    const int quad = lane >> 4;

    const uint4* fr = (const uint4*)ws;

    // block-cooperative staging of the three weight-frag images
    for (int idx = t; idx < 1536; idx += 256) wfr[idx] = fr[idx];
    __syncthreads();

    const int g = blockIdx.x * WPB + wv;
    if (g >= NGROUPS) return;

    float*  phig_s = &lds[wv][0];
    uint_t* utr    = (uint_t*)(phig_s + 520);
    float*  dxyz   = (float*)(utr + 544);
    float*  pxyz_s = dxyz + 128;

    // small per-lane constants
    float4 wc[4];
    float ba_r[4], gbr[4];
    #pragma unroll
    for (int nt = 0; nt < 4; ++nt) {
        int d = nt * 16 + c16;
        wc[nt]   = ((const float4*)(ws + WC4))[d];
        ba_r[nt] = ws[BA + d];
        gbr[nt]  = ws[GB + d];
    }

    const int g0 = g * GPW;
    const int k3 = lane / 3, c3 = lane - k3 * 3;   // lane<48: (neighbor, component)

    // ---- preamble ----
    if (lane < 24) pxyz_s[lane] = pxyz[g0 * 3 + lane];
    float nv0 = (lane < 48) ? nxyz[(size_t)g0 * 48 + lane] : 0.f;
    if (lane < 48) dxyz[k3 * 4 + c3] = pxyz_s[c3] - nv0;   // point 0, buf 0

    // phig = pf@(Wphi@Wg) + gb for the 8 points
    {
        float4 x0{}, x1{}, x2{}, x3{};
        if (c16 < 8) {
            const float* base = pfeat + (size_t)(g0 + c16) * 64 + quad * 8;
            x0 = *(const float4*)(base);
            x1 = *(const float4*)(base + 4);
            x2 = *(const float4*)(base + 32);
            x3 = *(const float4*)(base + 36);
        }
        Frag pa0, pa1;
        pa0.u[0] = pk(x0.x, x0.y); pa0.u[1] = pk(x0.z, x0.w);
        pa0.u[2] = pk(x1.x, x1.y); pa0.u[3] = pk(x1.z, x1.w);
        pa1.u[0] = pk(x2.x, x2.y); pa1.u[1] = pk(x2.z, x2.w);
        pa1.u[2] = pk(x3.x, x3.y); pa1.u[3] = pk(x3.z, x3.w);
        #pragma unroll
        for (int nt = 0; nt < 4; ++nt) {
            Frag b0, b1;
            b0.v = fr[1536 + (nt * 2 + 0) * 64 + lane];
            b1.v = fr[1536 + (nt * 2 + 1) * 64 + lane];
            f32x4 acc = {gbr[nt], gbr[nt], gbr[nt], gbr[nt]};
            acc = MFMA(pa0.s, b0.s, acc);
            acc = MFMA(pa1.s, b1.s, acc);
            if (quad < 2) {
                #pragma unroll
                for (int r = 0; r < 4; ++r)
                    phig_s[(quad * 4 + r) * 65 + nt * 16 + c16] = acc[r];
            }
        }
    }

    // depth-2 nf prefetch: pf0 = point 0, pf1 = point 1
    const float* nfb = nfeat + (size_t)g0 * (KNB * 64) + (size_t)c16 * 64 + quad * 8;
    float4 pf0[4], pf1[4];
    pf0[0] = *(const float4*)(nfb);
    pf0[1] = *(const float4*)(nfb + 4);
    pf0[2] = *(const float4*)(nfb + 32);
    pf0[3] = *(const float4*)(nfb + 36);
    {
        const float* nf1 = nfb + (KNB * 64);
        pf1[0] = *(const float4*)(nf1);
        pf1[1] = *(const float4*)(nf1 + 4);
        pf1[2] = *(const float4*)(nf1 + 32);
        pf1[3] = *(const float4*)(nf1 + 36);
    }
    float nvn = (lane < 48) ? nxyz[(size_t)g0 * 48 + 48 + lane] : 0.f;

    auto do_point = [&](int i, float4 (&pf)[4]) {
        const int n = g0 + i;

        // pack current nf A-frags, then refill this buffer for point i+2
        Frag na0, na1;
        na0.u[0] = pk(pf[0].x, pf[0].y); na0.u[1] = pk(pf[0].z, pf[0].w);
        na0.u[2] = pk(pf[1].x, pf[1].y); na0.u[3] = pk(pf[1].z, pf[1].w);
        na1.u[0] = pk(pf[2].x, pf[2].y); na1.u[1] = pk(pf[2].z, pf[2].w);
        na1.u[2] = pk(pf[3].x, pf[3].y); na1.u[3] = pk(pf[3].z, pf[3].w);
        if (i + 2 < GPW) {
            const float* nf2 = nfb + (size_t)(i + 2) * (KNB * 64);
            pf[0] = *(const float4*)(nf2);
            pf[1] = *(const float4*)(nf2 + 4);
            pf[2] = *(const float4*)(nf2 + 32);
            pf[3] = *(const float4*)(nf2 + 36);
        }

        // opaque offset: stops LICM from hoisting the LDS weight frags into VGPRs
        uint_t woff = 0;
        asm volatile("" : "+v"(woff));

        // early LDS reads: phig values, this point's dxyz rows
        float ph[4];
        #pragma unroll
        for (int nt = 0; nt < 4; ++nt) ph[nt] = phig_s[i * 65 + nt * 16 + c16];
        float4 dd[4];
        #pragma unroll
        for (int r = 0; r < 4; ++r)
            dd[r] = ((const float4*)dxyz)[(i & 1) * 16 + quad * 4 + r];

        // write next point's dxyz, then prefetch nxyz for i+2
        if (i + 1 < GPW) {
            if (lane < 48)
                dxyz[((i + 1) & 1) * 64 + k3 * 4 + c3] = pxyz_s[(i + 1) * 3 + c3] - nvn;
            if (i + 2 < GPW)
                nvn = (lane < 48) ? nxyz[((size_t)n + 2) * 48 + lane] : 0.f;
        }

        // delta in C-layout; pack transpose into utr
        float d_c[4][4];
        #pragma unroll
        for (int nt = 0; nt < 4; ++nt) {
            #pragma unroll
            for (int r = 0; r < 4; ++r) {
                float u = fmaf(dd[r].x, wc[nt].x,
                          fmaf(dd[r].y, wc[nt].y,
                          fmaf(dd[r].z, wc[nt].z, wc[nt].w)));
                d_c[nt][r] = fmaxf(u, 0.f);
            }
        }
        #pragma unroll
        for (int r = 0; r < 4; ++r) {
            int row = (quad * 4 + r) * 34;
            utr[row + c16]      = pk(d_c[0][r], d_c[1][r]);
            utr[row + 16 + c16] = pk(d_c[2][r], d_c[3][r]);
        }

        // alpha = nf@Wa + ba   (Wa frags from LDS)
        f32x4 aacc[4];
        #pragma unroll
        for (int nt = 0; nt < 4; ++nt) {
            Frag b0, b1;
            b0.v = wfr[woff + (nt * 2 + 0) * 64 + lane];
            b1.v = wfr[woff + (nt * 2 + 1) * 64 + lane];
            aacc[nt] = f32x4{ba_r[nt], ba_r[nt], ba_r[nt], ba_r[nt]};
            aacc[nt] = MFMA(na0.s, b0.s, aacc[nt]);
            aacc[nt] = MFMA(na1.s, b1.s, aacc[nt]);
        }
        // gamma = phig - nf@WpsiG   (frags from LDS)
        f32x4 gacc[4];
        #pragma unroll
        for (int nt = 0; nt < 4; ++nt) {
            Frag b0, b1;
            b0.v = wfr[woff + 512 + (nt * 2 + 0) * 64 + lane];
            b1.v = wfr[woff + 512 + (nt * 2 + 1) * 64 + lane];
            gacc[nt] = f32x4{ph[nt], ph[nt], ph[nt], ph[nt]};
            gacc[nt] = MFMA(na0.s, b0.s, gacc[nt]);
            gacc[nt] = MFMA(na1.s, b1.s, gacc[nt]);
        }
        // alpha finalize early so d_c dies
        #pragma unroll
        for (int nt = 0; nt < 4; ++nt)
            #pragma unroll
            for (int r = 0; r < 4; ++r) aacc[nt][r] += d_c[nt][r];

        // delta@Wg: read transposed delta back as A-frags, Wg frags from LDS
        Frag da0, da1;
        {
            const uint_t* rowp = utr + c16 * 34 + quad * 4;
            uint2 a = *(const uint2*)(rowp);
            uint2 b = *(const uint2*)(rowp + 2);
            uint2 c = *(const uint2*)(rowp + 16);
            uint2 d = *(const uint2*)(rowp + 18);
            da0.u[0] = a.x; da0.u[1] = a.y; da0.u[2] = b.x; da0.u[3] = b.y;
            da1.u[0] = c.x; da1.u[1] = c.y; da1.u[2] = d.x; da1.u[3] = d.y;
        }
        #pragma unroll
        for (int nt = 0; nt < 4; ++nt) {
            Frag b0, b1;
            b0.v = wfr[woff + 1024 + (nt * 2 + 0) * 64 + lane];
            b1.v = wfr[woff + 1024 + (nt * 2 + 1) * 64 + lane];
            gacc[nt] = MFMA(da0.s, b0.s, gacc[nt]);
            gacc[nt] = MFMA(da1.s, b1.s, gacc[nt]);
        }

        // softmax over features (no max-sub: |gamma| small by construction)
        float e[4][4], smi[4];
        #pragma unroll
        for (int r = 0; r < 4; ++r) {
            float s = 0.f;
            #pragma unroll
            for (int nt = 0; nt < 4; ++nt) { e[nt][r] = __expf(gacc[nt][r]); s += e[nt][r]; }
            #pragma unroll
            for (int d2 = 1; d2 < 16; d2 <<= 1) s += __shfl_xor(s, d2);
            smi[r] = __builtin_amdgcn_rcpf(s);
        }
        // out_d = sum_k rho*alpha
        float p0 = 0.f, p1 = 0.f, p2 = 0.f, p3 = 0.f;
        #pragma unroll
        for (int r = 0; r < 4; ++r) {
            p0 = fmaf(e[0][r] * smi[r], aacc[0][r], p0);
            p1 = fmaf(e[1][r] * smi[r], aacc[1][r], p1);
            p2 = fmaf(e[2][r] * smi[r], aacc[2][r], p2);
            p3 = fmaf(e[3][r] * smi[r], aacc[3][r], p3);
        }
        p0 += __shfl_xor(p0, 16); p0 += __shfl_xor(p0, 32);
        p1 += __shfl_xor(p1, 16); p1 += __shfl_xor(p1, 32);
        p2 += __shfl_xor(p2, 16); p2 += __shfl_xor(p2, 32);
        p3 += __shfl_xor(p3, 16); p3 += __shfl_xor(p3, 32);
        float sel = (quad == 0) ? p0 : (quad == 1) ? p1 : (quad == 2) ? p2 : p3;
        out[(size_t)n * 64 + lane] = sel;
    };

    #pragma unroll 1
    for (int ii = 0; ii < GPW / 2; ++ii) {
        do_point(2 * ii,     pf0);
        do_point(2 * ii + 1, pf1);
    }
}

extern "C" void kernel_launch(void* const* d_in, const int* in_sizes, int n_in,
                              void* d_out, int out_size, void* d_ws, size_t ws_size,
                              hipStream_t stream) {
    const float* pxyz  = (const float*)d_in[0];
    const float* pfeat = (const float*)d_in[1];
    const float* nxyz  = (const float*)d_in[2];
    const float* nfeat = (const float*)d_in[3];
    const float* Wphi  = (const float*)d_in[4];
    const float* bphi  = (const float*)d_in[5];
    const float* Wpsi  = (const float*)d_in[6];
    const float* bpsi  = (const float*)d_in[7];
    const float* Wa    = (const float*)d_in[8];
    const float* ba    = (const float*)d_in[9];
    const float* Wg    = (const float*)d_in[10];
    const float* bg    = (const float*)d_in[11];
    const float* Wd1   = (const float*)d_in[12];
    const float* bd1   = (const float*)d_in[13];
    const float* Wd2   = (const float*)d_in[14];
    const float* bd2   = (const float*)d_in[15];
    float* ws = (float*)d_ws;

    pt_prep<<<33, 256, 0, stream>>>(Wphi, bphi, Wpsi, bpsi, Wa, ba, Wg, bg,
                                    Wd1, bd1, Wd2, bd2, ws);
    pt_main<<<NBLOCKS, 256, 0, stream>>>(pxyz, pfeat, nxyz, nfeat, ws, (float*)d_out);
}